// Round 10
// baseline (254.232 us; speedup 1.0000x reference)
//
#include <hip/hip_runtime.h>
#include <hip/hip_bf16.h>
#include <stdint.h>

#define NB 32
#define NS 2048
#define ND 1024
#define NA 1024
#define MASK_NEG 1e30f

#define BM 256
#define BN 256
#define BK 64
#define NTILES 64  // 4 a-tiles x 16 K-tiles

typedef __attribute__((ext_vector_type(4))) float f32x4;
typedef __attribute__((ext_vector_type(8))) __bf16 bf16x8;

__device__ __forceinline__ void glds16(const void* g, void* l) {
  __builtin_amdgcn_global_load_lds(
      (const __attribute__((address_space(1))) uint32_t*)g,
      (__attribute__((address_space(3))) uint32_t*)(uintptr_t)l, 16, 0, 0);
}

// ---------------- fp32 -> bf16 bulk convert ----------------
__global__ __launch_bounds__(256) void cvt_bf16(const float* __restrict__ in,
                                                __bf16* __restrict__ out, int n8) {
  long i = blockIdx.x * 256 + threadIdx.x;
  const long stride = (long)gridDim.x * 256;
  for (; i < n8; i += stride) {
    f32x4 a = ((const f32x4*)in)[2 * i];
    f32x4 b = ((const f32x4*)in)[2 * i + 1];
    bf16x8 o;
#pragma unroll
    for (int j = 0; j < 4; ++j) { o[j] = (__bf16)a[j]; o[4 + j] = (__bf16)b[j]; }
    ((bf16x8*)out)[i] = o;
  }
}

// ---------------- w1q[b,a] = query[b,:] . W1[a,:]  (fp32) ----------------
__global__ __launch_bounds__(256) void w1q_kernel(const float* __restrict__ q,
                                                  const float* __restrict__ W1,
                                                  float* __restrict__ w1q) {
  const int b = blockIdx.x;
  const int a0 = blockIdx.y * 64;
  const int t = threadIdx.x;
  const int al = t >> 2;
  const int part = t & 3;
  const float* wrow = W1 + (size_t)(a0 + al) * ND + part * 256;
  const float* qrow = q + (size_t)b * ND + part * 256;
  float sum = 0.f;
#pragma unroll 8
  for (int i = 0; i < 256; i += 4) {
    float4 w = *reinterpret_cast<const float4*>(wrow + i);
    float4 x = *reinterpret_cast<const float4*>(qrow + i);
    sum += w.x * x.x + w.y * x.y + w.z * x.z + w.w * x.w;
  }
  __shared__ float red[256];
  red[t] = sum;
  __syncthreads();
  if (t < 64) {
    w1q[(size_t)b * NA + a0 + t] = red[t * 4] + red[t * 4 + 1] + red[t * 4 + 2] + red[t * 4 + 3];
  }
}

// ---------------- fused scores GEMM: R8 stagger, compiler-scheduled phases ----------------
// Same staggered half-tile schedule + vmcnt(2) counting as R8 (verified):
//   ph1:A(t1,h1) ph2:B(t1,h0) ph3:B(t1,h1) ph4:A(t0+2,h0)+vm
//   ph5:A(t0+2,h1) ph6:B(t0+2,h0) ph7:B(t0+2,h1) ph8:A(t1+2,h0)+vm
// CHANGED vs R8: one barrier per phase (at start); NO pinned lgkmcnt(0)
// before the MFMA cluster -- the compiler emits counted lgkm per MFMA
// dependency, so MFMAs start when their first fragments land and remaining
// ds_reads overlap MFMA (m196 interleave lever). Safety invariant kept: a
// trailing lgkmcnt(0) (free -- reads already consumed) before the next BAR
// guarantees slot reads complete before that slot's restage.
__global__ __launch_bounds__(512, 1) void score_gemm8(
    const __bf16* __restrict__ keysb, const __bf16* __restrict__ W2b,
    const float* __restrict__ w1q, const float* __restrict__ vvec,
    float* __restrict__ scores) {
  __shared__ __bf16 ldsA[4][128 * BK];  // [slot*2+half][...] 64 KB
  __shared__ __bf16 ldsB[4][128 * BK];  // 64 KB
  __shared__ float sm_w1q[NA];          // 4 KB
  __shared__ float sm_v[NA];            // 4 KB
  __shared__ float sm_part[4][BM];      // 4 KB

  const int t = threadIdx.x;
  const int bs0 = blockIdx.x * BM;
  const int b = bs0 >> 11;  // / NS
  const int lane = t & 63;
  const int wid = t >> 6;
  const int wr = wid >> 2;   // 0..1: 128-row half of output
  const int wc = wid & 3;    // 0..3: 64-col quarter; B-half = wc>>1
  const int lrow = lane & 15;
  const int ko = lane >> 4;

  for (int i = t; i < NA; i += 512) {
    sm_w1q[i] = w1q[(size_t)b * NA + i];
    sm_v[i] = vvec[i];
  }
  for (int i = t; i < 4 * BM; i += 512) ((float*)sm_part)[i] = 0.f;

  // staging lane geometry (R2-verified involution): 1 glds = 1 KB = 8 rows of
  // 128 B; this thread stages rows wid*16+j*8+srow (j=0,1) of each half-tile.
  const int srow = lane >> 3;
  const int scol = (lane & 7) ^ srow;
  const size_t aoffT = (size_t)(bs0 + wid * 16 + srow) * ND + scol * 8;
  const size_t boffT = (size_t)(wid * 16 + srow) * ND + scol * 8;

  // fragment read slots (pre-swizzled; row offsets are multiples of 8)
  const int sl0 = ko ^ (lrow & 7);
  const int sl1 = (4 + ko) ^ (lrow & 7);

#define STAGE_A(T, H)                                                           \
  do {                                                                          \
    if ((T) < NTILES) {                                                         \
      char* d_ = (char*)ldsA + (((((T)&1) << 1) + (H)) << 14) + wid * 2048;     \
      const size_t g_ = aoffT + (size_t)((H)*128) * ND + (size_t)(((T)&15) * BK); \
      glds16(keysb + g_, d_);                                                   \
      glds16(keysb + g_ + (size_t)8 * ND, d_ + 1024);                           \
    }                                                                           \
  } while (0)

#define STAGE_B(T, H)                                                           \
  do {                                                                          \
    if ((T) < NTILES) {                                                         \
      char* d_ = (char*)ldsB + (((((T)&1) << 1) + (H)) << 14) + wid * 2048;     \
      const size_t g_ = boffT + (size_t)(((T) >> 4) * 256 + (H)*128) * ND +     \
                        (size_t)(((T)&15) * BK);                                \
      glds16(W2b + g_, d_);                                                     \
      glds16(W2b + g_ + (size_t)8 * ND, d_ + 1024);                             \
    }                                                                           \
  } while (0)

#define SB __builtin_amdgcn_sched_barrier(0)
#define P1 __builtin_amdgcn_s_setprio(1)
#define P0 __builtin_amdgcn_s_setprio(0)
#define BAR __builtin_amdgcn_s_barrier()

  // PHASE: BAR -> stage 1 half-tile -> reads (af only on N_==0; reused on
  // N_==1) -> MFMA (compiler-counted lgkm; reads/MFMA interleave) ->
  // trailing lgkm(0) (free) -> [counted vmcnt at ph4/ph8].
#define PHASE(TL, M_, N_, STAGE_STMT, WM)                                       \
  do {                                                                          \
    BAR;                                                                        \
    SB;                                                                         \
    STAGE_STMT;                                                                 \
    if ((N_) == 0) {                                                            \
      const char* Ab_ = (const char*)ldsA + (((((TL)&1) << 1) | wr) << 14);     \
      _Pragma("unroll") for (int mi = 0; mi < 4; ++mi) {                        \
        const int ra_ = (((M_)*4 + mi) * 16 + lrow) * 128;                      \
        af[mi][0] = *reinterpret_cast<const bf16x8*>(Ab_ + ra_ + sl0 * 16);     \
        af[mi][1] = *reinterpret_cast<const bf16x8*>(Ab_ + ra_ + sl1 * 16);     \
      }                                                                         \
    }                                                                           \
    {                                                                           \
      const char* Bb_ = (const char*)ldsB + (((((TL)&1) << 1) | (wc >> 1)) << 14); \
      _Pragma("unroll") for (int nq = 0; nq < 2; ++nq) {                        \
        const int rb_ = (((wc & 1) * 4 + (N_)*2 + nq) * 16 + lrow) * 128;       \
        bfr[nq][0] = *reinterpret_cast<const bf16x8*>(Bb_ + rb_ + sl0 * 16);    \
        bfr[nq][1] = *reinterpret_cast<const bf16x8*>(Bb_ + rb_ + sl1 * 16);    \
      }                                                                         \
    }                                                                           \
    P1;                                                                         \
    _Pragma("unroll") for (int mi = 0; mi < 4; ++mi)                            \
        _Pragma("unroll") for (int nq = 0; nq < 2; ++nq) {                      \
      acc[(M_)*4 + mi][(N_)*2 + nq] = __builtin_amdgcn_mfma_f32_16x16x32_bf16(  \
          af[mi][0], bfr[nq][0], acc[(M_)*4 + mi][(N_)*2 + nq], 0, 0, 0);       \
      acc[(M_)*4 + mi][(N_)*2 + nq] = __builtin_amdgcn_mfma_f32_16x16x32_bf16(  \
          af[mi][1], bfr[nq][1], acc[(M_)*4 + mi][(N_)*2 + nq], 0, 0, 0);       \
    }                                                                           \
    P0;                                                                         \
    asm volatile("s_waitcnt lgkmcnt(0)");                                       \
    SB;                                                                         \
    if (WM) {                                                                   \
      if (it != 31) { asm volatile("s_waitcnt vmcnt(2)"); }                     \
      else { asm volatile("s_waitcnt vmcnt(0)"); }                              \
      SB;                                                                       \
    }                                                                           \
  } while (0)

  f32x4 acc[8][4];
#pragma unroll
  for (int mi = 0; mi < 8; ++mi)
#pragma unroll
    for (int ni = 0; ni < 4; ++ni) acc[mi][ni] = f32x4{0.f, 0.f, 0.f, 0.f};

  bf16x8 af[4][2], bfr[2][2];

  // ---- prologue: A(0,*), B(0,*), A(1,h0); drain once ----
  STAGE_A(0, 0);
  STAGE_A(0, 1);
  STAGE_B(0, 0);
  STAGE_B(0, 1);
  STAGE_A(1, 0);
  __syncthreads();  // drains vmcnt/lgkm; also sm_* init

  for (int it = 0; it < 32; ++it) {
    const int t0 = 2 * it, t1 = 2 * it + 1;
    PHASE(t0, 0, 0, STAGE_A(t1, 1), 0);       // ph1
    PHASE(t0, 0, 1, STAGE_B(t1, 0), 0);       // ph2
    PHASE(t0, 1, 0, STAGE_B(t1, 1), 0);       // ph3
    PHASE(t0, 1, 1, STAGE_A(t0 + 2, 0), 1);   // ph4 + vmcnt(2)
    PHASE(t1, 0, 0, STAGE_A(t0 + 2, 1), 0);   // ph5
    PHASE(t1, 0, 1, STAGE_B(t0 + 2, 0), 0);   // ph6
    PHASE(t1, 1, 0, STAGE_B(t0 + 2, 1), 0);   // ph7
    PHASE(t1, 1, 1, STAGE_A(t1 + 2, 0), 1);   // ph8 + vmcnt(2)

    // ---- per-a-tile epilogue: tanh + v-weight -> sm_part ----
    if ((it & 7) == 7) {
      const int a0 = (it >> 3) * BN;
      float w1v[4], vv[4];
#pragma unroll
      for (int ni = 0; ni < 4; ++ni) {
        const int a = a0 + wc * 64 + ni * 16 + lrow;
        w1v[ni] = sm_w1q[a];
        vv[ni] = sm_v[a];
      }
#pragma unroll
      for (int mi = 0; mi < 8; ++mi)
#pragma unroll
        for (int r = 0; r < 4; ++r) {
          float p = 0.f;
#pragma unroll
          for (int ni = 0; ni < 4; ++ni) {
            const float x = acc[mi][ni][r] + w1v[ni];
            const float e = __expf(2.f * x);
            p += (1.f - 2.f * __builtin_amdgcn_rcpf(e + 1.f)) * vv[ni];
          }
          p += __shfl_xor(p, 1);
          p += __shfl_xor(p, 2);
          p += __shfl_xor(p, 4);
          p += __shfl_xor(p, 8);
          if (lrow == 0) sm_part[wc][wr * 128 + mi * 16 + ko * 4 + r] += p;
        }
#pragma unroll
      for (int mi = 0; mi < 8; ++mi)
#pragma unroll
        for (int ni = 0; ni < 4; ++ni) acc[mi][ni] = f32x4{0.f, 0.f, 0.f, 0.f};
    }
  }

  __syncthreads();
  if (t < BM)
    scores[bs0 + t] = sm_part[0][t] + sm_part[1][t] + sm_part[2][t] + sm_part[3][t];

#undef STAGE_A
#undef STAGE_B
#undef PHASE
#undef SB
#undef P1
#undef P0
#undef BAR
}

// ---------------- masked softmax ----------------
__global__ __launch_bounds__(256) void softmax_kernel(const float* __restrict__ scores,
                                                      const int* __restrict__ mask,
                                                      float* __restrict__ out) {
  const int b = blockIdx.x;
  const int t = threadIdx.x;
  float sc[8];
  float mx = -3.4e38f;
#pragma unroll
  for (int j = 0; j < 8; ++j) {
    int i = t + j * 256;
    float s = scores[b * NS + i];
    if (mask[b * NS + i] == 0) s -= MASK_NEG;
    sc[j] = s;
    mx = fmaxf(mx, s);
  }
#pragma unroll
  for (int off = 1; off < 64; off <<= 1) mx = fmaxf(mx, __shfl_xor(mx, off));
  __shared__ float redm[4];
  __shared__ float reds[4];
  if ((t & 63) == 0) redm[t >> 6] = mx;
  __syncthreads();
  mx = fmaxf(fmaxf(redm[0], redm[1]), fmaxf(redm[2], redm[3]));
  float e[8];
  float sum = 0.f;
#pragma unroll
  for (int j = 0; j < 8; ++j) {
    e[j] = __expf(sc[j] - mx);
    sum += e[j];
  }
#pragma unroll
  for (int off = 1; off < 64; off <<= 1) sum += __shfl_xor(sum, off);
  if ((t & 63) == 0) reds[t >> 6] = sum;
  __syncthreads();
  sum = reds[0] + reds[1] + reds[2] + reds[3];
  float inv = 1.f / sum;
#pragma unroll
  for (int j = 0; j < 8; ++j) out[b * NS + t + j * 256] = e[j] * inv;
}

extern "C" void kernel_launch(void* const* d_in, const int* in_sizes, int n_in,
                              void* d_out, int out_size, void* d_ws, size_t ws_size,
                              hipStream_t stream) {
  const float* q = (const float*)d_in[0];
  const float* keysf = (const float*)d_in[1];
  const int* mask = (const int*)d_in[2];
  const float* W1 = (const float*)d_in[3];
  const float* W2f = (const float*)d_in[4];
  const float* v = (const float*)d_in[5];
  float* out = (float*)d_out;

  float* scores = (float*)d_ws;                                 // 256 KB
  float* w1q = scores + NB * NS;                                // 128 KB
  __bf16* W2b = (__bf16*)(w1q + NB * NA);                       // 2 MB
  __bf16* keysb = (__bf16*)((char*)W2b + (size_t)NA * ND * 2);  // 128 MB

  cvt_bf16<<<512, 256, 0, stream>>>(W2f, W2b, NA * ND / 8);
  cvt_bf16<<<2048, 256, 0, stream>>>(keysf, keysb, (int)((size_t)NB * NS * ND / 8));
  w1q_kernel<<<dim3(NB, NA / 64), 256, 0, stream>>>(q, W1, w1q);
  score_gemm8<<<NB * NS / BM, 512, 0, stream>>>(keysb, W2b, w1q, v, scores);
  softmax_kernel<<<NB, 256, 0, stream>>>(scores, mask, out);
}